// Round 7
// baseline (67.278 us; speedup 1.0000x reference)
//
#include <hip/hip_runtime.h>
#include <hip/hip_bf16.h>
#include <cstdint>

#define SS   2048
#define DD   128
#define KBLK 64
#define NKT  32                      // key tiles per batch
#define TILE_BYTES 16384             // 64x128 bf16 (K) or 128x64 bf16 (Vt)

// ---- v7 (CHUNK=4) workspace ----
#define NBLK7 1152
#define WS_K    ((size_t)0)
#define WS_V    ((size_t)16 * NKT * TILE_BYTES)             // 8 MB
#define WS_PO7  ((size_t)16 * NKT * TILE_BYTES * 2)         // 16 MB
#define WS_ML7  (WS_PO7 + (size_t)NBLK7 * 128 * 128 * 2)    // +37.75 MB
#define WS_NEED7 (WS_ML7 + (size_t)NBLK7 * 128 * 4)         // ~54.9 MB

// ---- v6 (CHUNK=8) fallback workspace ----
#define NBLK6 640
#define WS_PO6  ((size_t)16 * NKT * TILE_BYTES * 2)
#define WS_ML6  (WS_PO6 + (size_t)NBLK6 * 128 * 128 * 2)
#define WS_NEED6 (WS_ML6 + (size_t)NBLK6 * 128 * 4)         // ~36.4 MB

typedef __attribute__((ext_vector_type(8)))  short short8;   // 8 bf16 (MFMA A/B)
typedef __attribute__((ext_vector_type(16))) float f32x16;   // 32x32 MFMA C/D

__device__ __forceinline__ unsigned short f2bf(float x) {
  return __builtin_bit_cast(unsigned short, (__bf16)x);
}
__device__ __forceinline__ float bfbits2f(unsigned int lo16shifted) {
  return __builtin_bit_cast(float, lo16shifted);
}

// ---- v7 chunk tables: q-block i has T_i = 2i+2 tiles, chunks of <=4 ----
__device__ __constant__ unsigned char SLOT_BASE[16] = {0,1,2,4,6,9,12,16,20,25,30,36,42,49,56,64};
__device__ __constant__ unsigned char NCH[16]       = {1,1,2,2,3,3,4,4,5,5,6,6,7,7,8,8};
__device__ __constant__ unsigned char SLOT_I[72] = {
  0,1,2,2,3,3,4,4,4,5,5,5,6,6,6,6,7,7,7,7,
  8,8,8,8,8,9,9,9,9,9,10,10,10,10,10,10,11,11,11,11,11,11,
  12,12,12,12,12,12,12,13,13,13,13,13,13,13,
  14,14,14,14,14,14,14,14,15,15,15,15,15,15,15,15};

// ---- v6 chunk tables (CHUNK=8 fallback) ----
__device__ __constant__ unsigned char FULLI[28]   = {3,4,5,6,7,7,8,8,9,9,10,10,11,11,11,12,12,12,13,13,13,14,14,14,15,15,15,15};
__device__ __constant__ unsigned char FULLBASE[16]= {0,0,0,0,1,2,3,4,6,8,10,12,15,18,21,24};
__device__ __constant__ unsigned char FULLCNT[16] = {0,0,0,1,1,1,1,2,2,2,2,3,3,3,3,4};
__device__ __constant__ signed   char SMALLIDX[16]= {0,1,2,-1,3,4,5,-1,6,7,8,-1,9,10,11,-1};
__device__ __constant__ unsigned char SMALLI[12]  = {0,1,2,4,5,6,8,9,10,12,13,14};
__device__ __constant__ unsigned char SMALLC[12]  = {0,0,0,1,1,1,2,2,2,3,3,3};
__device__ __constant__ unsigned char SMALLN[12]  = {2,4,6,2,4,6,2,4,6,2,4,6};

// ---------------------------------------------------------------------------
// Pre-pass: K -> bf16 row-major swizzled tiles; V -> transposed pi-permuted
// swizzled tiles Vt[d][slot] (PV A-frag slots == lane's own QK^T outputs).
// ---------------------------------------------------------------------------
__global__ __launch_bounds__(256) void prepack_kv7(
    const float* __restrict__ K, const float* __restrict__ V, char* __restrict__ ws)
{
  __shared__ float vf[64][129];
  const int b = blockIdx.x, t = blockIdx.y;
  const int tid = threadIdx.x;
  const float* Kt = K + ((size_t)b * SS + t * KBLK) * DD;
  const float* Vt = V + ((size_t)b * SS + t * KBLK) * DD;
  char* Kd = ws + WS_K + ((size_t)(b * NKT + t)) * TILE_BYTES;
  char* Vd = ws + WS_V + ((size_t)(b * NKT + t)) * TILE_BYTES;

  #pragma unroll
  for (int u = 0; u < 4; ++u) {
    int row = u * 16 + (tid >> 4);
    int col = 8 * (tid & 15);
    const float4* sp = reinterpret_cast<const float4*>(Kt + (size_t)row * DD + col);
    float4 x = sp[0], y = sp[1];
    short8 w;
    w[0] = f2bf(x.x); w[1] = f2bf(x.y); w[2] = f2bf(x.z); w[3] = f2bf(x.w);
    w[4] = f2bf(y.x); w[5] = f2bf(y.y); w[6] = f2bf(y.z); w[7] = f2bf(y.w);
    int off = (row * 256 + col * 2) ^ ((row & 7) << 4);
    *reinterpret_cast<short8*>(Kd + off) = w;
  }
  #pragma unroll
  for (int u = 0; u < 4; ++u) {
    int row = u * 16 + (tid >> 4);
    int col = 8 * (tid & 15);
    const float4* sp = reinterpret_cast<const float4*>(Vt + (size_t)row * DD + col);
    float4 x = sp[0], y = sp[1];
    vf[row][col+0]=x.x; vf[row][col+1]=x.y; vf[row][col+2]=x.z; vf[row][col+3]=x.w;
    vf[row][col+4]=y.x; vf[row][col+5]=y.y; vf[row][col+6]=y.z; vf[row][col+7]=y.w;
  }
  __syncthreads();
  #pragma unroll
  for (int q = 0; q < 4; ++q) {
    int idx = q * 256 + tid;
    int d = idx >> 3, y8 = idx & 7;
    short8 w;
    #pragma unroll
    for (int j = 0; j < 8; ++j) {
      int a = ((y8 >> 2) << 5) | (((y8 >> 1) & 1) << 4) | ((j >> 2) << 3) | (j & 3) | ((y8 & 1) << 2);
      w[j] = f2bf(vf[a][d]);
    }
    int off = ((d << 7) + (y8 << 4)) ^ ((d & 7) << 4);
    *reinterpret_cast<short8*>(Vd + off) = w;
  }
}

__device__ __forceinline__ void stage_tile(const char* Ksrc, const char* Vsrc,
                                           char* Kl, char* Vl, int wid, int lane)
{
  #pragma unroll
  for (int i = 0; i < 4; ++i) {
    int off = wid * 4096 + i * 1024;
    __builtin_amdgcn_global_load_lds(
        (const __attribute__((address_space(1))) unsigned int*)(Ksrc + off + lane * 16),
        (__attribute__((address_space(3))) unsigned int*)(Kl + off), 16, 0, 0);
  }
  #pragma unroll
  for (int i = 0; i < 4; ++i) {
    int off = wid * 4096 + i * 1024;
    __builtin_amdgcn_global_load_lds(
        (const __attribute__((address_space(1))) unsigned int*)(Vsrc + off + lane * 16),
        (__attribute__((address_space(3))) unsigned int*)(Vl + off), 16, 0, 0);
  }
}

// ---------------------------------------------------------------------------
// Shared per-block attention body (chunk [kvt0, kvt0+ntile) of q-block i).
// ---------------------------------------------------------------------------
template <int MAXT>
__device__ __forceinline__ void attn_chunk_body(
    const float* Qb, const char* Kws, const char* Vws, char* smem,
    int i, int kvt0, int ntile, int wid, int lane,
    f32x16 (&o)[4], float& lsum, short8 (&qf)[8])
{
  const int l31 = lane & 31;
  const int h   = lane >> 5;
  const int qg  = 128 * i + wid * 32 + l31;

  stage_tile(Kws + (size_t)kvt0 * TILE_BYTES, Vws + (size_t)kvt0 * TILE_BYTES,
             smem, smem + 16384, wid, lane);
  __syncthreads();

  for (int t = 0; t < ntile; ++t) {
    const char* Kl = smem;
    const char* Vl = smem + 16384;
    const int tt = kvt0 + t;
    const bool domask = tt >= 2 * i;

    short8 pf[4];
    float psum = 0.f;

    #pragma unroll
    for (int g = 0; g < 2; ++g) {
      f32x16 acc;
      #pragma unroll
      for (int r = 0; r < 16; ++r) acc[r] = 0.f;
      const int key = g * 32 + l31;
      const int kbase = key * 256 + h * 16;
      const int kswz = (key & 7) << 4;
      __builtin_amdgcn_s_setprio(1);
      #pragma unroll
      for (int s = 0; s < 8; ++s) {
        short8 kf = *reinterpret_cast<const short8*>(Kl + ((kbase + s * 32) ^ kswz));
        acc = __builtin_amdgcn_mfma_f32_32x32x16_bf16(kf, qf[s], acc, 0, 0, 0);
      }
      __builtin_amdgcn_s_setprio(0);

      if (domask) {
        const int kb = tt * 64 + g * 32 + 4 * h;
        #pragma unroll
        for (int r = 0; r < 16; ++r) {
          int keyg = kb + (r & 3) + 8 * (r >> 2);
          if (keyg > qg) acc[r] = -1e30f;
        }
      }

      float pg[16];
      #pragma unroll
      for (int r = 0; r < 16; ++r) pg[r] = exp2f(acc[r]);
      float s0 = ((pg[0]+pg[1])+(pg[2]+pg[3])) + ((pg[4]+pg[5])+(pg[6]+pg[7]));
      float s1 = ((pg[8]+pg[9])+(pg[10]+pg[11])) + ((pg[12]+pg[13])+(pg[14]+pg[15]));
      psum += s0 + s1;

      short8 w0, w1;
      #pragma unroll
      for (int j = 0; j < 8; ++j) { w0[j] = f2bf(pg[j]); w1[j] = f2bf(pg[8 + j]); }
      pf[2 * g]     = w0;
      pf[2 * g + 1] = w1;
    }
    lsum += psum;

    __builtin_amdgcn_s_setprio(1);
    #pragma unroll
    for (int dg = 0; dg < 4; ++dg) {
      const int d = dg * 32 + l31;
      const int vbase = d * 128 + h * 16;
      const int vswz = (d & 7) << 4;
      #pragma unroll
      for (int s4 = 0; s4 < 4; ++s4) {
        short8 vf8 = *reinterpret_cast<const short8*>(Vl + ((vbase + s4 * 32) ^ vswz));
        o[dg] = __builtin_amdgcn_mfma_f32_32x32x16_bf16(vf8, pf[s4], o[dg], 0, 0, 0);
      }
    }
    __builtin_amdgcn_s_setprio(0);

    if (t + 1 < ntile) {
      __syncthreads();
      stage_tile(Kws + (size_t)(tt + 1) * TILE_BYTES, Vws + (size_t)(tt + 1) * TILE_BYTES,
                 smem, smem + 16384, wid, lane);
      __syncthreads();
    }
  }
}

__device__ __forceinline__ void load_qfrag(const float* Qb, int qg, int h,
                                           short8 (&qf)[8])
{
  const float qscale = 0.08838834764831845f * 1.4426950408889634f; // 1/sqrt(128)*log2(e)
  const float* qrow = Qb + (size_t)qg * DD;
  #pragma unroll
  for (int s = 0; s < 8; ++s) {
    const float4* p = reinterpret_cast<const float4*>(qrow + s * 16 + h * 8);
    float4 x = p[0], z = p[1];
    short8 w;
    w[0] = f2bf(x.x * qscale); w[1] = f2bf(x.y * qscale);
    w[2] = f2bf(x.z * qscale); w[3] = f2bf(x.w * qscale);
    w[4] = f2bf(z.x * qscale); w[5] = f2bf(z.y * qscale);
    w[6] = f2bf(z.z * qscale); w[7] = f2bf(z.w * qscale);
    qf[s] = w;
  }
}

// ---------------------------------------------------------------------------
// v7 main: CHUNK=4 -> 1152 blocks (4.5/CU). Single 32KB LDS buffer; natural
// VGPR (~104) -> 4 waves/SIMD; inter-block overlap hides stage drain.
// ---------------------------------------------------------------------------
__global__ __launch_bounds__(256) void sdpa_v7(
    const float* __restrict__ Q, const char* __restrict__ ws,
    float* __restrict__ O, unsigned short* __restrict__ partO,
    float* __restrict__ partML)
{
  __shared__ __align__(16) char smem[32768];

  const int y = blockIdx.x;
  const int b = y & 15;
  const int slot = y >> 4;
  const int i = SLOT_I[slot];
  const int c = slot - SLOT_BASE[i];
  const int nch = NCH[i];
  const int ntile = (c == nch - 1) ? (2 * i + 2 - 4 * c) : 4;
  const int kvt0 = 4 * c;
  const bool dostore = (nch == 1);

  const int tid  = threadIdx.x;
  const int lane = tid & 63;
  const int wid  = tid >> 6;
  const int l31  = lane & 31;
  const int h    = lane >> 5;

  const float* Qb  = Q + (size_t)b * SS * DD;
  const char*  Kws = ws + WS_K + ((size_t)(b * NKT)) * TILE_BYTES;
  const char*  Vws = ws + WS_V + ((size_t)(b * NKT)) * TILE_BYTES;

  const int qg = 128 * i + wid * 32 + l31;

  short8 qf[8];
  load_qfrag(Qb, qg, h, qf);

  f32x16 o[4];
  #pragma unroll
  for (int dg = 0; dg < 4; ++dg)
    #pragma unroll
    for (int r = 0; r < 16; ++r) o[dg][r] = 0.f;
  float lsum = 0.f;

  attn_chunk_body<4>(Qb, Kws, Vws, smem, i, kvt0, ntile, wid, lane, o, lsum, qf);

  lsum += __shfl_xor(lsum, 32);

  if (dostore) {
    float inv = 1.0f / lsum;
    float* Ob = O + (size_t)b * SS * DD + (size_t)qg * DD;
    #pragma unroll
    for (int dg = 0; dg < 4; ++dg)
      #pragma unroll
      for (int rq = 0; rq < 4; ++rq) {
        int d0 = dg * 32 + 8 * rq + 4 * h;
        float4 w;
        w.x = o[dg][4 * rq + 0] * inv;
        w.y = o[dg][4 * rq + 1] * inv;
        w.z = o[dg][4 * rq + 2] * inv;
        w.w = o[dg][4 * rq + 3] * inv;
        *reinterpret_cast<float4*>(Ob + d0) = w;
      }
  } else {
    unsigned short* po = partO + (size_t)y * (128 * 128) + (size_t)(wid * 32 + l31) * 128;
    #pragma unroll
    for (int dg = 0; dg < 4; ++dg)
      #pragma unroll
      for (int rq = 0; rq < 4; ++rq) {
        int d0 = dg * 32 + 8 * rq + 4 * h;
        ushort4 u;
        u.x = f2bf(o[dg][4 * rq + 0]);
        u.y = f2bf(o[dg][4 * rq + 1]);
        u.z = f2bf(o[dg][4 * rq + 2]);
        u.w = f2bf(o[dg][4 * rq + 3]);
        *reinterpret_cast<ushort4*>(po + d0) = u;
      }
    if (h == 0) partML[y * 128 + wid * 32 + l31] = lsum;
  }
}

// Merge for i>=2: O[b][128i+row][:] = (sum_c U_c) / (sum_c l_c)
__global__ __launch_bounds__(256) void merge_v7(
    const unsigned short* __restrict__ partO, const float* __restrict__ partML,
    float* __restrict__ O)
{
  const int b = blockIdx.x;
  const int i = blockIdx.y + 2;
  const int rg = blockIdx.z;
  const int tid = threadIdx.x;
  const int row = rg * 32 + (tid >> 3);
  const int c0  = (tid & 7) * 16;

  float acc[16];
  #pragma unroll
  for (int u = 0; u < 16; ++u) acc[u] = 0.f;
  float ltot = 0.f;

  const int nch = NCH[i];
  const int base = SLOT_BASE[i];

  for (int c = 0; c < nch; ++c) {
    int slot = (base + c) * 16 + b;
    ltot += partML[slot * 128 + row];
    const uint4* po = reinterpret_cast<const uint4*>(
        partO + (size_t)slot * (128 * 128) + (size_t)row * 128 + c0);
    #pragma unroll
    for (int u = 0; u < 2; ++u) {
      uint4 v = po[u];
      acc[u*8+0] += bfbits2f(v.x << 16); acc[u*8+1] += bfbits2f(v.x & 0xffff0000u);
      acc[u*8+2] += bfbits2f(v.y << 16); acc[u*8+3] += bfbits2f(v.y & 0xffff0000u);
      acc[u*8+4] += bfbits2f(v.z << 16); acc[u*8+5] += bfbits2f(v.z & 0xffff0000u);
      acc[u*8+6] += bfbits2f(v.w << 16); acc[u*8+7] += bfbits2f(v.w & 0xffff0000u);
    }
  }
  float inv = 1.0f / ltot;
  float* orow = O + ((size_t)b * SS + 128 * i + row) * DD + c0;
  #pragma unroll
  for (int u = 0; u < 4; ++u) {
    float4 w;
    w.x = acc[4*u+0] * inv; w.y = acc[4*u+1] * inv;
    w.z = acc[4*u+2] * inv; w.w = acc[4*u+3] * inv;
    reinterpret_cast<float4*>(orow)[u] = w;
  }
}

// ---------------------------------------------------------------------------
// v6 fallback (CHUNK=8, 640 blocks) if ws too small for v7
// ---------------------------------------------------------------------------
__global__ __launch_bounds__(256) void sdpa_v6f(
    const float* __restrict__ Q, const char* __restrict__ ws,
    unsigned short* __restrict__ partO, float* __restrict__ partML)
{
  __shared__ __align__(16) char smem[32768];

  const int y = blockIdx.x;
  int b, i, c, ntile;
  if (y < 448) { int k = y >> 4; b = y & 15; i = FULLI[k]; c = k - FULLBASE[i]; ntile = 8; }
  else         { int z = y - 448; int k = z >> 4; b = z & 15; i = SMALLI[k]; c = SMALLC[k]; ntile = SMALLN[k]; }

  const int tid  = threadIdx.x;
  const int lane = tid & 63;
  const int wid  = tid >> 6;
  const int l31  = lane & 31;
  const int h    = lane >> 5;

  const float* Qb  = Q + (size_t)b * SS * DD;
  const char*  Kws = ws + WS_K + ((size_t)(b * NKT)) * TILE_BYTES;
  const char*  Vws = ws + WS_V + ((size_t)(b * NKT)) * TILE_BYTES;

  const int qg = 128 * i + wid * 32 + l31;
  short8 qf[8];
  load_qfrag(Qb, qg, h, qf);

  f32x16 o[4];
  #pragma unroll
  for (int dg = 0; dg < 4; ++dg)
    #pragma unroll
    for (int r = 0; r < 16; ++r) o[dg][r] = 0.f;
  float lsum = 0.f;

  attn_chunk_body<8>(Qb, Kws, Vws, smem, i, 8 * c, ntile, wid, lane, o, lsum, qf);

  lsum += __shfl_xor(lsum, 32);

  unsigned short* po = partO + (size_t)y * (128 * 128) + (size_t)(wid * 32 + l31) * 128;
  #pragma unroll
  for (int dg = 0; dg < 4; ++dg)
    #pragma unroll
    for (int rq = 0; rq < 4; ++rq) {
      int d0 = dg * 32 + 8 * rq + 4 * h;
      ushort4 u;
      u.x = f2bf(o[dg][4 * rq + 0]);
      u.y = f2bf(o[dg][4 * rq + 1]);
      u.z = f2bf(o[dg][4 * rq + 2]);
      u.w = f2bf(o[dg][4 * rq + 3]);
      *reinterpret_cast<ushort4*>(po + d0) = u;
    }
  if (h == 0) partML[y * 128 + wid * 32 + l31] = lsum;
}

__global__ __launch_bounds__(256) void merge_v6f(
    const unsigned short* __restrict__ partO, const float* __restrict__ partML,
    float* __restrict__ O)
{
  const int x = blockIdx.x;
  const int b = x & 15, i = (x >> 4) & 15, rg = x >> 8;
  const int tid = threadIdx.x;
  const int row = rg * 32 + (tid >> 3);
  const int c0  = (tid & 7) * 16;

  float acc[16];
  #pragma unroll
  for (int u = 0; u < 16; ++u) acc[u] = 0.f;
  float ltot = 0.f;

  const int nf = FULLCNT[i];
  const int si = SMALLIDX[i];
  const int nch = nf + (si >= 0 ? 1 : 0);

  for (int c = 0; c < nch; ++c) {
    int slot = (c < nf) ? ((FULLBASE[i] + c) * 16 + b) : (448 + si * 16 + b);
    ltot += partML[slot * 128 + row];
    const uint4* po = reinterpret_cast<const uint4*>(
        partO + (size_t)slot * (128 * 128) + (size_t)row * 128 + c0);
    #pragma unroll
    for (int u = 0; u < 2; ++u) {
      uint4 v = po[u];
      acc[u*8+0] += bfbits2f(v.x << 16); acc[u*8+1] += bfbits2f(v.x & 0xffff0000u);
      acc[u*8+2] += bfbits2f(v.y << 16); acc[u*8+3] += bfbits2f(v.y & 0xffff0000u);
      acc[u*8+4] += bfbits2f(v.z << 16); acc[u*8+5] += bfbits2f(v.z & 0xffff0000u);
      acc[u*8+6] += bfbits2f(v.w << 16); acc[u*8+7] += bfbits2f(v.w & 0xffff0000u);
    }
  }
  float inv = 1.0f / ltot;
  float* orow = O + ((size_t)b * SS + 128 * i + row) * DD + c0;
  #pragma unroll
  for (int u = 0; u < 4; ++u) {
    float4 w;
    w.x = acc[4*u+0] * inv; w.y = acc[4*u+1] * inv;
    w.z = acc[4*u+2] * inv; w.w = acc[4*u+3] * inv;
    reinterpret_cast<float4*>(orow)[u] = w;
  }
}

extern "C" void kernel_launch(void* const* d_in, const int* in_sizes, int n_in,
                              void* d_out, int out_size, void* d_ws, size_t ws_size,
                              hipStream_t stream) {
  const float* Q = (const float*)d_in[0];
  const float* K = (const float*)d_in[1];
  const float* V = (const float*)d_in[2];
  float* O = (float*)d_out;
  char* ws = (char*)d_ws;

  if (ws_size >= WS_NEED7) {
    unsigned short* partO = (unsigned short*)(ws + WS_PO7);
    float* partML = (float*)(ws + WS_ML7);
    prepack_kv7<<<dim3(16, NKT), 256, 0, stream>>>(K, V, ws);
    sdpa_v7<<<dim3(NBLK7), 256, 0, stream>>>(Q, ws, O, partO, partML);
    merge_v7<<<dim3(16, 14, 4), 256, 0, stream>>>(partO, partML, O);
  } else {
    unsigned short* partO = (unsigned short*)(ws + WS_PO6);
    float* partML = (float*)(ws + WS_ML6);
    prepack_kv7<<<dim3(16, NKT), 256, 0, stream>>>(K, V, ws);
    sdpa_v6f<<<dim3(NBLK6), 256, 0, stream>>>(Q, ws, partO, partML);
    merge_v6f<<<dim3(1024), 256, 0, stream>>>(partO, partML, O);
  }
}